// Round 13
// baseline (263.840 us; speedup 1.0000x reference)
//
#include <hip/hip_runtime.h>

#define B_    8
#define C_    96
#define H_    96
#define W_    96
#define HW_   9216
#define CHW_  884736
#define BCHW_ 7077888
#define OUTHALF_ 14155776
#define PAD_  98

typedef __attribute__((ext_vector_type(8))) short short8;
typedef __attribute__((ext_vector_type(4))) float f32x4;

__device__ __forceinline__ unsigned short f2bf(float f) {
    unsigned u = __builtin_bit_cast(unsigned, f);
    u = (u + 0x7FFFu + ((u >> 16) & 1u)) >> 16;
    return (unsigned short)u;
}
__device__ __forceinline__ float bf2f(unsigned short h) {
    return __builtin_bit_cast(float, (unsigned)h << 16);
}

__device__ __forceinline__ void gll16(const void* g, void* l) {
    __builtin_amdgcn_global_load_lds((const __attribute__((address_space(1))) void*)g,
                                     (__attribute__((address_space(3))) void*)l, 16, 0, 0);
}

// ---------------------------------------------------------------------------
// Pack concat(x1,x2) -> padded NHWC bf16 xb[8][98][98][192], zero border.
// Extra grid row (yp==98): zero the border of vb (padded NHWC 96ch).
__global__ __launch_bounds__(256) void pack_x_kernel(
    const float* __restrict__ x1, const float* __restrict__ x2,
    unsigned short* __restrict__ xb, unsigned short* __restrict__ vb)
{
    __shared__ unsigned short lds[192*100];
    const int tid = threadIdx.x;
    const int yp = blockIdx.x;      // 0..98
    const int b  = blockIdx.y;
    if (yp == 98) {                 // vb border zero for batch b
        unsigned short* vbb = vb + (size_t)b*PAD_*PAD_*96;
        for (int i = tid; i < 2*9408; i += 256) {   // rows 0 and 97 (full)
            int r = (i < 9408) ? 0 : 97;
            int o = (i < 9408) ? i : i - 9408;
            vbb[((size_t)r*PAD_)*96 + o] = 0;
        }
        for (int i = tid; i < 96*192; i += 256) {   // cols 0 and 97, rows 1..96
            int y = 1 + (i / 192);
            int rem = i % 192;
            int side = rem / 96;                    // 0 = col 0, 1 = col 97
            int c = rem % 96;
            vbb[((size_t)y*PAD_ + side*97)*96 + c] = 0;
        }
        return;
    }
    unsigned short* row = xb + ((size_t)(b*PAD_) + yp)*PAD_*192;
    if (yp == 0 || yp == PAD_-1) {
        for (int i = tid; i < PAD_*192; i += 256) row[i] = 0;
        return;
    }
    const int y = yp - 1;
    for (int i = tid; i < 2*HW_; i += 256) {
        const float* src = (i < HW_) ? x1 : x2;
        int ii = (i < HW_) ? i : i - HW_;
        int ch = ii / 96, x = ii - ch*96;
        int c = (i < HW_) ? ch : ch + 96;
        lds[c*100 + x] = f2bf(src[((size_t)(b*96 + ch))*HW_ + y*96 + x]);
    }
    __syncthreads();
    for (int i = tid; i < PAD_*192; i += 256) {
        int xp = i / 192, c = i - xp*192;
        row[i] = (xp == 0 || xp == PAD_-1) ? (unsigned short)0 : lds[c*100 + (xp-1)];
    }
}

// ---------------------------------------------------------------------------
// All 5 weight packs fused + zero the raw BN-stats accumulator.
// STEP ORDER (round-13): step%9 = s9 = kw*3 + kh (kw-major!) to match the
// conv's kw-outer/kh-inner loop. kh = s9%3, kw = s9/3.
__global__ __launch_bounds__(256) void pack_w_all_kernel(
    const float* __restrict__ w1, const float* __restrict__ w2,
    const float* __restrict__ wa1, const float* __restrict__ wa2,
    const float* __restrict__ wa3,
    unsigned short* __restrict__ wf1, unsigned short* __restrict__ wf2,
    unsigned short* __restrict__ wfa1, unsigned short* __restrict__ wfa2,
    unsigned short* __restrict__ wfa3, float* __restrict__ stats_raw)
{
    int i = blockIdx.x*256 + threadIdx.x;   // < 663552
    if (i < 576) stats_raw[i] = 0.f;
    const float* w; unsigned short* wf; int cin, rel;
    if      (i < 82944)  { w = w1;  wf = wf1;  cin = 96;  rel = i; }
    else if (i < 165888) { w = w2;  wf = wf2;  cin = 96;  rel = i - 82944; }
    else if (i < 331776) { w = wa1; wf = wfa1; cin = 192; rel = i - 165888; }
    else if (i < 497664) { w = wa2; wf = wfa2; cin = 192; rel = i - 331776; }
    else                 { w = wa3; wf = wfa3; cin = 192; rel = i - 497664; }
    int j = rel & 7;
    int lane = (rel >> 3) & 63;
    int blk = rel >> 9;
    int mf = blk % 6;
    int step = blk / 6;
    int chunk = step / 9, s9 = step - chunk*9;
    int kh = s9 % 3, kw = s9 / 3;          // kw-major step order (round-13)
    int m = lane & 15, g = lane >> 4;
    int co = mf*16 + m;
    int ci = chunk*32 + g*8 + j;
    wf[rel] = f2bf(w[(((size_t)co*cin + ci)*3 + kh)*3 + kw]);
}

// ---------------------------------------------------------------------------
// Fused implicit-GEMM 3x3 conv via MFMA, multi-job, templated on ROWS.
// Round-13: kw-OUTER / kh-INNER with B-fragment REGISTER CACHE. A wave's
// B-fragments for (r, kh) span only RWAVE+2 rows; caching frag[RWAVE+2][2]
// per kw halves LDS reads (72->36 per chunk: 6 MFMA per ds_read_b128 vs 3).
// Round-9 arithmetic: LDS was the binding pipe (770cy/tap vs MFMA 233cy,
// MfmaUtil 35%); W-L2 stays latency-hidden (depth-3 wq, slot=kh, 3|9 parity).
// Wave map: (wm,wp) = 48 couts x (ROWS/2 rows x 32 px) (round-11 lesson:
// don't shift load to W). No min-waves cap (round-8: capping spills acc).
struct ConvJobs {
    const unsigned short* xin[5];
    const unsigned short* wf[5];
    unsigned short* out[5];
    int chunks[5];
    int ci0[5];
    int mode[5];
    int wstride[5];
    int cistr[5];
    int dobn[5];
    int bnslot[5];
};

template<int ROWS>
__global__ __launch_bounds__(256) void conv_mfma_kernel(
    ConvJobs j, float* __restrict__ stats_raw, int njobs)
{
    constexpr int RWAVE = ROWS/2;            // rows per wave
    constexpr int NPOS  = (ROWS+2)*34;       // staged positions (halo rows)
    constexpr int NISS  = (NPOS + 15)/16;    // stage issues (22 or 13)
    __shared__ __align__(16) unsigned short xs[2][NISS*512];
    const int tid  = threadIdx.x;
    const int lane = tid & 63;
    const int wid  = tid >> 6;
    const int wm   = wid & 1;     // cout half (48)
    const int wp   = wid >> 1;    // pixel-row half
    const int x0 = blockIdx.x*32, y0 = blockIdx.y*ROWS;
    const int which = blockIdx.z % njobs, b = blockIdx.z / njobs;
    const int CHUNKS = j.chunks[which];
    const int CISTR  = j.cistr[which];
    const int ci0_base = j.ci0[which];
    const int NSTEP = CHUNKS*9;
    const unsigned short* xbb = j.xin[which] + (size_t)b*PAD_*PAD_*CISTR;
    const unsigned short* wfb = j.wf[which] + (size_t)b*j.wstride[which];

    auto stage = [&](int chunk, int buf) {
        int ci0 = ci0_base + chunk*32;
        for (int r = wid; r < NISS; r += 4) {
            int gi = r*64 + lane;
            int pos = gi >> 2; if (pos > NPOS-1) pos = NPOS-1;
            int g = gi & 3;
            int gsrc = (g ^ pos) & 3;               // XOR granule swizzle
            int ty = pos / 34, tx = pos - ty*34;
            gll16(xbb + ((size_t)(y0 + ty)*PAD_ + (x0 + tx))*CISTR + ci0 + gsrc*8,
                  &xs[buf][r*512]);
        }
    };
    auto loadWd = [&](int step, short8* dst) {
        const unsigned short* wstep = wfb + (size_t)step*3072;
        dst[0] = *(const short8*)(wstep + ((wm*3+0)*64 + lane)*8);
        dst[1] = *(const short8*)(wstep + ((wm*3+1)*64 + lane)*8);
        dst[2] = *(const short8*)(wstep + ((wm*3+2)*64 + lane)*8);
    };

    f32x4 acc[3][2*RWAVE];
    f32x4 zero = {0.f, 0.f, 0.f, 0.f};
#pragma unroll
    for (int a = 0; a < 3; ++a)
#pragma unroll
        for (int f = 0; f < 2*RWAVE; ++f) acc[a][f] = zero;

    short8 wq[3][3];            // [slot=kh][a]; steps are kw-major so slot=s9%3=kh
    loadWd(0, wq[0]);
    loadWd(1 < NSTEP ? 1 : 0, wq[1]);
    loadWd(2 < NSTEP ? 2 : 0, wq[2]);
    stage(0, 0);
    __syncthreads();

    const int n = lane & 15, gw = lane >> 4;
    for (int chunk = 0; chunk < CHUNKS; ++chunk) {
        const int cur = chunk & 1;
        if (chunk + 1 < CHUNKS) stage(chunk + 1, cur ^ 1);   // issue; fly under MFMAs
#pragma unroll
        for (int kw = 0; kw < 3; ++kw) {
            // B-fragment register cache for this kw: RWAVE+2 rows x 2 col-halves
            short8 frag[RWAVE+2][2];
#pragma unroll
            for (int row = 0; row < RWAVE+2; ++row) {
#pragma unroll
                for (int xh = 0; xh < 2; ++xh) {
                    int pos = (wp*RWAVE + row)*34 + (xh*16 + n + kw);
                    int g = (gw ^ pos) & 3;
                    frag[row][xh] = *(const short8*)(&xs[cur][pos*32 + g*8]);
                }
            }
#pragma unroll
            for (int kh = 0; kh < 3; ++kh) {
                const int step = chunk*9 + kw*3 + kh;
                short8 wa0 = wq[kh][0], wa1 = wq[kh][1], wa2 = wq[kh][2];
                int pf = step + 3; if (pf >= NSTEP) pf = NSTEP - 1;
                loadWd(pf, wq[kh]);                          // prefetch (kw+1, kh)
#pragma unroll
                for (int r = 0; r < RWAVE; ++r) {
#pragma unroll
                    for (int xh = 0; xh < 2; ++xh) {
                        short8 bfrag = frag[r + kh][xh];     // static index (unrolled)
                        int f = r*2 + xh;
                        acc[0][f] = __builtin_amdgcn_mfma_f32_16x16x32_bf16(wa0, bfrag, acc[0][f], 0, 0, 0);
                        acc[1][f] = __builtin_amdgcn_mfma_f32_16x16x32_bf16(wa1, bfrag, acc[1][f], 0, 0, 0);
                        acc[2][f] = __builtin_amdgcn_mfma_f32_16x16x32_bf16(wa2, bfrag, acc[2][f], 0, 0, 0);
                    }
                }
            }
        }
        __syncthreads();   // drains stage(next); protects xs[cur] reuse
    }

    // epilogue: C/D layout col=lane&15 (pixel), row=(lane>>4)*4+reg (cout).
    if (j.mode[which] == 1) {
        unsigned short* out = j.out[which];
#pragma unroll
        for (int a = 0; a < 3; ++a)
#pragma unroll
        for (int r = 0; r < RWAVE; ++r)
#pragma unroll
        for (int xh = 0; xh < 2; ++xh) {
            int y = y0 + wp*RWAVE + r, x = x0 + xh*16 + n;
#pragma unroll
            for (int reg = 0; reg < 4; ++reg) {
                int co = wm*48 + a*16 + gw*4 + reg;
                out[((size_t)(b*96 + co))*HW_ + y*96 + x] = f2bf(acc[a][r*2+xh][reg]);
            }
        }
    } else {
        unsigned short* out = j.out[which];  // padded NHWC, 96 ch
#pragma unroll
        for (int a = 0; a < 3; ++a)
#pragma unroll
        for (int r = 0; r < RWAVE; ++r)
#pragma unroll
        for (int xh = 0; xh < 2; ++xh) {
            int y = y0 + wp*RWAVE + r, x = x0 + xh*16 + n;
            int cb = wm*48 + a*16 + gw*4;
            f32x4 v = acc[a][r*2+xh];
            uint2 pv;
            pv.x = (unsigned)f2bf(v[0]) | ((unsigned)f2bf(v[1]) << 16);
            pv.y = (unsigned)f2bf(v[2]) | ((unsigned)f2bf(v[3]) << 16);
            *(uint2*)(out + ((size_t)(b*PAD_ + y+1)*PAD_ + (x+1))*96 + cb) = pv;
        }
    }

    // fused BN partial sums (y1/y2/y3 jobs).
    if (j.dobn[which]) {
        float* lds_s = (float*)&xs[0][0];
        float* lds_q = lds_s + 96;
        if (tid < 192) lds_s[tid] = 0.f;
        __syncthreads();
#pragma unroll
        for (int a = 0; a < 3; ++a)
#pragma unroll
        for (int reg = 0; reg < 4; ++reg) {
            float s = 0.f, q2 = 0.f;
#pragma unroll
            for (int f = 0; f < 2*RWAVE; ++f) { float v = acc[a][f][reg]; s += v; q2 += v*v; }
#pragma unroll
            for (int m = 1; m < 16; m <<= 1) {
                s  += __shfl_xor(s, m);
                q2 += __shfl_xor(q2, m);
            }
            if (n == 0) {
                int co = wm*48 + a*16 + gw*4 + reg;
                atomicAdd(&lds_s[co], s);
                atomicAdd(&lds_q[co], q2);
            }
        }
        __syncthreads();
        if (tid < 96) {
            int t = j.bnslot[which];
            atomicAdd(stats_raw + t*96 + tid, lds_s[tid]);
            atomicAdd(stats_raw + 288 + t*96 + tid, lds_q[tid]);
        }
    }
}

// ---------------------------------------------------------------------------
// Repack q,k NCHW bf16 -> tap-major [b][tap(9)][ch(96)][L=1024] via LDS.
__global__ __launch_bounds__(256) void repack_qk_kernel(
    const unsigned short* __restrict__ qb, const unsigned short* __restrict__ kb,
    unsigned short* __restrict__ qt, unsigned short* __restrict__ kt)
{
    __shared__ unsigned short q_lds[HW_], k_lds[HW_];
    const int tid = threadIdx.x;
    const int ch = blockIdx.x, b = blockIdx.y;
    const unsigned short* qsrc = qb + ((size_t)(b*96 + ch))*HW_;
    const unsigned short* ksrc = kb + ((size_t)(b*96 + ch))*HW_;
    for (int i = tid; i < HW_/8; i += 256) {
        *(short8*)(&q_lds[i*8]) = *(const short8*)(qsrc + i*8);
        *(short8*)(&k_lds[i*8]) = *(const short8*)(ksrc + i*8);
    }
    __syncthreads();
    const int l0 = tid*4;
    const int i0 = l0 >> 5, j0 = l0 & 31;
    for (int tap = 0; tap < 9; ++tap) {
        int kh = tap/3, kw = tap - kh*3;
        int base = (3*i0 + kh)*96 + kw;
        ushort4 vq, vk;
        vq.x = q_lds[base + 3*(j0+0)]; vq.y = q_lds[base + 3*(j0+1)];
        vq.z = q_lds[base + 3*(j0+2)]; vq.w = q_lds[base + 3*(j0+3)];
        vk.x = k_lds[base + 3*(j0+0)]; vk.y = k_lds[base + 3*(j0+1)];
        vk.z = k_lds[base + 3*(j0+2)]; vk.w = k_lds[base + 3*(j0+3)];
        size_t dst = (((size_t)(b*9 + tap))*96 + ch)*1024 + l0;
        *(ushort4*)(qt + dst) = vq;
        *(ushort4*)(kt + dst) = vk;
    }
}

// ---------------------------------------------------------------------------
// Gram partial: attnp[s][b][tap][cq][ck], L-split s in 0..3.
__global__ __launch_bounds__(256) void attn_mfma_kernel(
    const unsigned short* __restrict__ qt, const unsigned short* __restrict__ kt,
    float* __restrict__ attnp)
{
    __shared__ __align__(16) unsigned short qs[6144], ks[6144];
    const int tid = threadIdx.x, lane = tid & 63, wid = tid >> 6;
    const int tap = blockIdx.x, b = blockIdx.y, s = blockIdx.z;
    const int wm = wid & 1, wn = wid >> 1;
    const unsigned short* qbase = qt + ((size_t)(b*9 + tap))*96*1024;
    const unsigned short* kbase = kt + ((size_t)(b*9 + tap))*96*1024;

    f32x4 acc[3][3];
    f32x4 zero = {0.f, 0.f, 0.f, 0.f};
#pragma unroll
    for (int i = 0; i < 3; ++i)
#pragma unroll
        for (int j = 0; j < 3; ++j) acc[i][j] = zero;

    const int lrow = lane >> 3, lgr = lane & 7;
    for (int kc = 0; kc < 4; ++kc) {
        int L0 = s*256 + kc*64;
        for (int r = wid; r < 12; r += 4) {
            int row = r*8 + lrow;
            int gsrc = lgr ^ (row & 7);             // both-sides XOR swizzle
            gll16(qbase + (size_t)row*1024 + L0 + gsrc*8, &qs[r*512]);
        }
        for (int r = wid; r < 12; r += 4) {
            int row = r*8 + lrow;
            int gsrc = lgr ^ (row & 7);
            gll16(kbase + (size_t)row*1024 + L0 + gsrc*8, &ks[r*512]);
        }
        __syncthreads();
#pragma unroll
        for (int ks_ = 0; ks_ < 2; ++ks_) {
            short8 av[3], bv[3];
#pragma unroll
            for (int am = 0; am < 3; ++am) {
                int row = wm*48 + am*16 + (lane & 15);
                int gp = (ks_*4 + (lane >> 4)) ^ (row & 7);
                av[am] = *(const short8*)(&qs[row*64 + gp*8]);
            }
#pragma unroll
            for (int bn = 0; bn < 3; ++bn) {
                int row = wn*48 + bn*16 + (lane & 15);
                int gp = (ks_*4 + (lane >> 4)) ^ (row & 7);
                bv[bn] = *(const short8*)(&ks[row*64 + gp*8]);
            }
#pragma unroll
            for (int am = 0; am < 3; ++am)
#pragma unroll
                for (int bn = 0; bn < 3; ++bn)
                    acc[am][bn] = __builtin_amdgcn_mfma_f32_16x16x32_bf16(av[am], bv[bn], acc[am][bn], 0, 0, 0);
        }
        __syncthreads();
    }
    float* dst = attnp + ((((size_t)s*8 + b)*9 + tap))*9216;
#pragma unroll
    for (int am = 0; am < 3; ++am)
#pragma unroll
    for (int bn = 0; bn < 3; ++bn)
#pragma unroll
    for (int reg = 0; reg < 4; ++reg) {
        int cq = wm*48 + am*16 + (lane>>4)*4 + reg;
        int ck = wn*48 + bn*16 + (lane&15);
        dst[(size_t)cq*96 + ck] = acc[am][bn][reg];
    }
}

// ---------------------------------------------------------------------------
// softmax over m=(cq*9+tap); emits bf16 per-batch conv weights fragment-linear.
// Round-13: conv step order is kw-major (s9 = kw*3+kh); reference tap order is
// kh-major (tap = kh*3+kw) -> permute: s9 = (tap%3)*3 + tap/3.
__global__ __launch_bounds__(256) void softmax_kernel(
    const float* __restrict__ attnp, unsigned short* __restrict__ wfab)
{
    __shared__ float red[256];
    const int tid = threadIdx.x;
    const int ck = blockIdx.x % 96, b = blockIdx.x / 96;
    const float scale = 0.03402069087198858f;   // 1/sqrt(864)
    float v[4];
#pragma unroll
    for (int r = 0; r < 4; ++r) {
        int m = r*256 + tid;
        if (m < 864) {
            int cq = m / 9, tap = m - cq*9;
            const float* ap = attnp + ((((size_t)b*9 + tap))*96 + cq)*96 + ck;
            v[r] = (ap[0] + ap[663552] + ap[2*663552] + ap[3*663552]) * scale;
        } else v[r] = -1e30f;
    }
    float mx = fmaxf(fmaxf(v[0], v[1]), fmaxf(v[2], v[3]));
    red[tid] = mx; __syncthreads();
    for (int s = 128; s > 0; s >>= 1) {
        if (tid < s) red[tid] = fmaxf(red[tid], red[tid+s]);
        __syncthreads();
    }
    mx = red[0]; __syncthreads();
    float e[4]; float lsum = 0.f;
#pragma unroll
    for (int r = 0; r < 4; ++r) {
        int m = r*256 + tid;
        if (m < 864) { e[r] = __expf(v[r] - mx); lsum += e[r]; }
        else e[r] = 0.f;
    }
    red[tid] = lsum; __syncthreads();
    for (int s = 128; s > 0; s >>= 1) {
        if (tid < s) red[tid] += red[tid+s];
        __syncthreads();
    }
    float inv = 1.f / red[0];
#pragma unroll
    for (int r = 0; r < 4; ++r) {
        int m = r*256 + tid;
        if (m < 864) {
            int cq = m / 9, tap = m - cq*9;
            int s9 = (tap % 3)*3 + tap/3;           // kh-major -> kw-major
            int chunk = cq >> 5, cl = cq & 31, g = cl >> 3, j = cl & 7;
            int mf = ck >> 4, mrem = ck & 15;
            int lane2 = mrem + (g << 4);
            size_t oidx = (size_t)b*82944
                + ((((size_t)(chunk*9 + s9)*6 + mf)*64 + lane2)*8 + j);
            wfab[oidx] = f2bf(e[r]*inv);
        }
    }
}

// ---------------------------------------------------------------------------
// out0 = x + concat(bn(y1)*bn(y2), bn(y3)); out1 = x. BN stats computed
// inline from the conv-fused raw sums (s, s2) per channel.
__global__ __launch_bounds__(256) void final_kernel(
    const float* __restrict__ x1, const float* __restrict__ x2,
    const unsigned short* __restrict__ y1, const unsigned short* __restrict__ y2,
    const unsigned short* __restrict__ y3, const float* __restrict__ stats_raw,
    float* __restrict__ out)
{
    size_t q4 = (size_t)blockIdx.x*256 + threadIdx.x;  // quad id < 1769472
    size_t base = q4*4;
    int b  = (int)(base / CHW_);
    int c  = (int)((base / HW_) % 96);
    int hw = (int)(base % HW_);
    const float NN = 73728.f;
    float s1 = stats_raw[c],        qq1 = stats_raw[288 + c];
    float s2 = stats_raw[96 + c],   qq2 = stats_raw[384 + c];
    float s3 = stats_raw[192 + c],  qq3 = stats_raw[480 + c];
    float mu1 = s1/NN, mu2 = s2/NN, mu3 = s3/NN;
    float r1 = rsqrtf(qq1/NN - mu1*mu1 + 1e-5f);
    float r2 = rsqrtf(qq2/NN - mu2*mu2 + 1e-5f);
    float r3 = rsqrtf(qq3/NN - mu3*mu3 + 1e-5f);
    float4 x1v = *(const float4*)(x1 + base);
    float4 x2v = *(const float4*)(x2 + base);
    ushort4 a1 = *(const ushort4*)(y1 + base);
    ushort4 a2 = *(const ushort4*)(y2 + base);
    ushort4 a3 = *(const ushort4*)(y3 + base);
    size_t lo = ((size_t)(b*192 + c))*HW_ + hw;
    size_t hi = lo + (size_t)96*HW_;
    float4 o0, o1;
    o0.x = x1v.x + ((bf2f(a1.x)-mu1)*r1) * ((bf2f(a2.x)-mu2)*r2);
    o0.y = x1v.y + ((bf2f(a1.y)-mu1)*r1) * ((bf2f(a2.y)-mu2)*r2);
    o0.z = x1v.z + ((bf2f(a1.z)-mu1)*r1) * ((bf2f(a2.z)-mu2)*r2);
    o0.w = x1v.w + ((bf2f(a1.w)-mu1)*r1) * ((bf2f(a2.w)-mu2)*r2);
    o1.x = x2v.x + (bf2f(a3.x)-mu3)*r3;
    o1.y = x2v.y + (bf2f(a3.y)-mu3)*r3;
    o1.z = x2v.z + (bf2f(a3.z)-mu3)*r3;
    o1.w = x2v.w + (bf2f(a3.w)-mu3)*r3;
    *(float4*)(out + lo) = o0;
    *(float4*)(out + hi) = o1;
    *(float4*)(out + OUTHALF_ + lo) = x1v;
    *(float4*)(out + OUTHALF_ + hi) = x2v;
}

// ---------------------------------------------------------------------------
extern "C" void kernel_launch(void* const* d_in, const int* in_sizes, int n_in,
                              void* d_out, int out_size, void* d_ws, size_t ws_size,
                              hipStream_t stream)
{
    const float* x1  = (const float*)d_in[0];
    const float* x2  = (const float*)d_in[1];
    const float* w1  = (const float*)d_in[2];
    const float* w2  = (const float*)d_in[3];
    const float* wa1 = (const float*)d_in[4];
    const float* wa2 = (const float*)d_in[5];
    const float* wa3 = (const float*)d_in[6];
    float* out = (float*)d_out;
    char* ws = (char*)d_ws;

    unsigned short* xb   = (unsigned short*)(ws);             // 29,503,488 B
    unsigned short* y1b  = (unsigned short*)(ws + 29503488);  // 14,155,776 B
    unsigned short* y2b  = (unsigned short*)(ws + 43659264);
    unsigned short* y3b  = (unsigned short*)(ws + 57815040);
    unsigned short* wf1  = (unsigned short*)(ws + 71970816);  // 165,888 B
    unsigned short* wf2  = (unsigned short*)(ws + 72136704);
    unsigned short* wfa1 = (unsigned short*)(ws + 72302592);  // 331,776 B
    unsigned short* wfa2 = (unsigned short*)(ws + 72634368);
    unsigned short* wfa3 = (unsigned short*)(ws + 72966144);
    unsigned short* wfab = (unsigned short*)(ws + 73297920);  // 1,327,104 B
    float* stats_raw = (float*)(ws + 74625024);               // 2,304 B

    // d_out scratch (all dead before final_kernel):
    unsigned short* qb    = (unsigned short*)out;                       // 14,155,776 B
    unsigned short* kkb   = (unsigned short*)((char*)out + 14155776);   // 14,155,776 B
    unsigned short* vb    = (unsigned short*)((char*)out + 28311552);   // 14,751,744 B
    unsigned short* qt    = (unsigned short*)((char*)out + 43063296);   // 14,155,776 B
    unsigned short* kt    = (unsigned short*)((char*)out + 57219072);   // 14,155,776 B
    float*          attnp = (float*)((char*)out + 71374848);            // 10,616,832 B

    pack_w_all_kernel<<<2592, 256, 0, stream>>>(w1, w2, wa1, wa2, wa3,
                                                wf1, wf2, wfa1, wfa2, wfa3,
                                                stats_raw);
    pack_x_kernel<<<dim3(99, 8), 256, 0, stream>>>(x1, x2, xb, vb);

    ConvJobs jA;
    jA.xin[0]=xb;  jA.wf[0]=wfa1; jA.out[0]=qb;  jA.chunks[0]=6; jA.ci0[0]=0;  jA.mode[0]=1; jA.wstride[0]=0; jA.cistr[0]=192; jA.dobn[0]=0; jA.bnslot[0]=0;
    jA.xin[1]=xb;  jA.wf[1]=wfa2; jA.out[1]=kkb; jA.chunks[1]=6; jA.ci0[1]=0;  jA.mode[1]=1; jA.wstride[1]=0; jA.cistr[1]=192; jA.dobn[1]=0; jA.bnslot[1]=0;
    jA.xin[2]=xb;  jA.wf[2]=wfa3; jA.out[2]=vb;  jA.chunks[2]=6; jA.ci0[2]=0;  jA.mode[2]=2; jA.wstride[2]=0; jA.cistr[2]=192; jA.dobn[2]=0; jA.bnslot[2]=0;
    jA.xin[3]=xb;  jA.wf[3]=wf1;  jA.out[3]=y1b; jA.chunks[3]=3; jA.ci0[3]=0;  jA.mode[3]=1; jA.wstride[3]=0; jA.cistr[3]=192; jA.dobn[3]=1; jA.bnslot[3]=0;
    jA.xin[4]=xb;  jA.wf[4]=wf2;  jA.out[4]=y2b; jA.chunks[4]=3; jA.ci0[4]=96; jA.mode[4]=1; jA.wstride[4]=0; jA.cistr[4]=192; jA.dobn[4]=1; jA.bnslot[4]=1;
    conv_mfma_kernel<8><<<dim3(3, 12, 40), 256, 0, stream>>>(jA, stats_raw, 5);

    repack_qk_kernel<<<dim3(96, 8), 256, 0, stream>>>(qb, kkb, qt, kt);
    attn_mfma_kernel<<<dim3(9, 8, 4), 256, 0, stream>>>(qt, kt, attnp);
    softmax_kernel<<<768, 256, 0, stream>>>(attnp, wfab);

    ConvJobs jB;
    for (int s = 0; s < 5; ++s) {
        jB.xin[s]=vb; jB.wf[s]=wfab; jB.out[s]=y3b; jB.chunks[s]=3; jB.ci0[s]=0;
        jB.mode[s]=1; jB.wstride[s]=82944; jB.cistr[s]=96; jB.dobn[s]=1; jB.bnslot[s]=2;
    }
    conv_mfma_kernel<4><<<dim3(3, 24, 8), 256, 0, stream>>>(jB, stats_raw, 1);

    final_kernel<<<6912, 256, 0, stream>>>(x1, x2, y1b, y2b, y3b, stats_raw, out);
}

// Round 14
// 223.848 us; speedup vs baseline: 1.1787x; 1.1787x over previous
//
#include <hip/hip_runtime.h>

#define B_    8
#define C_    96
#define H_    96
#define W_    96
#define HW_   9216
#define CHW_  884736
#define BCHW_ 7077888
#define OUTHALF_ 14155776
#define PAD_  98

typedef __attribute__((ext_vector_type(8))) short short8;
typedef __attribute__((ext_vector_type(4))) float f32x4;

__device__ __forceinline__ unsigned short f2bf(float f) {
    unsigned u = __builtin_bit_cast(unsigned, f);
    u = (u + 0x7FFFu + ((u >> 16) & 1u)) >> 16;
    return (unsigned short)u;
}
__device__ __forceinline__ float bf2f(unsigned short h) {
    return __builtin_bit_cast(float, (unsigned)h << 16);
}

__device__ __forceinline__ void gll16(const void* g, void* l) {
    __builtin_amdgcn_global_load_lds((const __attribute__((address_space(1))) void*)g,
                                     (__attribute__((address_space(3))) void*)l, 16, 0, 0);
}

// ---------------------------------------------------------------------------
// Pack concat(x1,x2) -> padded NHWC bf16 xb[8][98][98][192], zero border.
// Extra grid row (yp==98): zero the border of vb (padded NHWC 96ch).
__global__ __launch_bounds__(256) void pack_x_kernel(
    const float* __restrict__ x1, const float* __restrict__ x2,
    unsigned short* __restrict__ xb, unsigned short* __restrict__ vb)
{
    __shared__ unsigned short lds[192*100];
    const int tid = threadIdx.x;
    const int yp = blockIdx.x;      // 0..98
    const int b  = blockIdx.y;
    if (yp == 98) {                 // vb border zero for batch b
        unsigned short* vbb = vb + (size_t)b*PAD_*PAD_*96;
        for (int i = tid; i < 2*9408; i += 256) {   // rows 0 and 97 (full)
            int r = (i < 9408) ? 0 : 97;
            int o = (i < 9408) ? i : i - 9408;
            vbb[((size_t)r*PAD_)*96 + o] = 0;
        }
        for (int i = tid; i < 96*192; i += 256) {   // cols 0 and 97, rows 1..96
            int y = 1 + (i / 192);
            int rem = i % 192;
            int side = rem / 96;                    // 0 = col 0, 1 = col 97
            int c = rem % 96;
            vbb[((size_t)y*PAD_ + side*97)*96 + c] = 0;
        }
        return;
    }
    unsigned short* row = xb + ((size_t)(b*PAD_) + yp)*PAD_*192;
    if (yp == 0 || yp == PAD_-1) {
        for (int i = tid; i < PAD_*192; i += 256) row[i] = 0;
        return;
    }
    const int y = yp - 1;
    for (int i = tid; i < 2*HW_; i += 256) {
        const float* src = (i < HW_) ? x1 : x2;
        int ii = (i < HW_) ? i : i - HW_;
        int ch = ii / 96, x = ii - ch*96;
        int c = (i < HW_) ? ch : ch + 96;
        lds[c*100 + x] = f2bf(src[((size_t)(b*96 + ch))*HW_ + y*96 + x]);
    }
    __syncthreads();
    for (int i = tid; i < PAD_*192; i += 256) {
        int xp = i / 192, c = i - xp*192;
        row[i] = (xp == 0 || xp == PAD_-1) ? (unsigned short)0 : lds[c*100 + (xp-1)];
    }
}

// ---------------------------------------------------------------------------
// All 5 weight packs fused + zero the raw BN-stats accumulator (576 floats,
// re-zeroed EVERY call so graph replays are correct). kh-major tap order.
__global__ __launch_bounds__(256) void pack_w_all_kernel(
    const float* __restrict__ w1, const float* __restrict__ w2,
    const float* __restrict__ wa1, const float* __restrict__ wa2,
    const float* __restrict__ wa3,
    unsigned short* __restrict__ wf1, unsigned short* __restrict__ wf2,
    unsigned short* __restrict__ wfa1, unsigned short* __restrict__ wfa2,
    unsigned short* __restrict__ wfa3, float* __restrict__ stats_raw)
{
    int i = blockIdx.x*256 + threadIdx.x;   // < 663552
    if (i < 576) stats_raw[i] = 0.f;
    const float* w; unsigned short* wf; int cin, rel;
    if      (i < 82944)  { w = w1;  wf = wf1;  cin = 96;  rel = i; }
    else if (i < 165888) { w = w2;  wf = wf2;  cin = 96;  rel = i - 82944; }
    else if (i < 331776) { w = wa1; wf = wfa1; cin = 192; rel = i - 165888; }
    else if (i < 497664) { w = wa2; wf = wfa2; cin = 192; rel = i - 331776; }
    else                 { w = wa3; wf = wfa3; cin = 192; rel = i - 497664; }
    int j = rel & 7;
    int lane = (rel >> 3) & 63;
    int blk = rel >> 9;
    int mf = blk % 6;
    int step = blk / 6;
    int chunk = step / 9, tap = step - chunk*9;
    int kh = tap / 3, kw = tap - kh*3;
    int m = lane & 15, g = lane >> 4;
    int co = mf*16 + m;
    int ci = chunk*32 + g*8 + j;
    wf[rel] = f2bf(w[(((size_t)co*cin + ci)*3 + kh)*3 + kw]);
}

// ---------------------------------------------------------------------------
// Fused implicit-GEMM 3x3 conv via MFMA, multi-job, templated on ROWS.
// VERIFIED-BEST configuration (round 12, 226 us): wave (wm,wp) = 48 couts x
// (ROWS/2 rows x 32 px); wq[3][3] depth-3 rotating W prefetch (3|9 parity);
// 2-phase X staging; no min-waves cap. Structural ceiling of this 2-barrier
// template ~830-900 TF (m97-class). Measured dead ends: pixel-only wave map
// (r11: doubles W-L2 traffic, -15%), kw-outer frag cache (r13: conflicts/read
// double + occupancy halves, -29%), ROWS=4 for big-input jobs (r7: kills
// cache reuse, FETCH 2.6x), launch_bounds(,3) (r8: spills acc to scratch).
struct ConvJobs {
    const unsigned short* xin[5];
    const unsigned short* wf[5];
    unsigned short* out[5];
    int chunks[5];
    int ci0[5];
    int mode[5];
    int wstride[5];
    int cistr[5];
    int dobn[5];
    int bnslot[5];
};

template<int ROWS>
__global__ __launch_bounds__(256) void conv_mfma_kernel(
    ConvJobs j, float* __restrict__ stats_raw, int njobs)
{
    constexpr int RWAVE = ROWS/2;            // rows per wave
    constexpr int NPOS  = (ROWS+2)*34;       // staged positions (halo rows)
    constexpr int NISS  = (NPOS + 15)/16;    // stage issues (22 or 13)
    __shared__ __align__(16) unsigned short xs[2][NISS*512];
    const int tid  = threadIdx.x;
    const int lane = tid & 63;
    const int wid  = tid >> 6;
    const int wm   = wid & 1;     // cout half (48)
    const int wp   = wid >> 1;    // pixel-row half
    const int x0 = blockIdx.x*32, y0 = blockIdx.y*ROWS;
    const int which = blockIdx.z % njobs, b = blockIdx.z / njobs;
    const int CHUNKS = j.chunks[which];
    const int CISTR  = j.cistr[which];
    const int ci0_base = j.ci0[which];
    const int NSTEP = CHUNKS*9;
    const unsigned short* xbb = j.xin[which] + (size_t)b*PAD_*PAD_*CISTR;
    const unsigned short* wfb = j.wf[which] + (size_t)b*j.wstride[which];

    auto stage = [&](int chunk, int buf) {
        int ci0 = ci0_base + chunk*32;
        for (int r = wid; r < NISS; r += 4) {
            int gi = r*64 + lane;
            int pos = gi >> 2; if (pos > NPOS-1) pos = NPOS-1;
            int g = gi & 3;
            int gsrc = (g ^ pos) & 3;               // XOR granule swizzle
            int ty = pos / 34, tx = pos - ty*34;
            gll16(xbb + ((size_t)(y0 + ty)*PAD_ + (x0 + tx))*CISTR + ci0 + gsrc*8,
                  &xs[buf][r*512]);
        }
    };
    auto loadWd = [&](int step, short8* dst) {
        const unsigned short* wstep = wfb + (size_t)step*3072;
        dst[0] = *(const short8*)(wstep + ((wm*3+0)*64 + lane)*8);
        dst[1] = *(const short8*)(wstep + ((wm*3+1)*64 + lane)*8);
        dst[2] = *(const short8*)(wstep + ((wm*3+2)*64 + lane)*8);
    };

    f32x4 acc[3][2*RWAVE];
    f32x4 zero = {0.f, 0.f, 0.f, 0.f};
#pragma unroll
    for (int a = 0; a < 3; ++a)
#pragma unroll
        for (int f = 0; f < 2*RWAVE; ++f) acc[a][f] = zero;

    short8 wq[3][3];            // [depth slot][a]; depth 3 divides 9 (parity!)
    loadWd(0, wq[0]);
    loadWd(1 < NSTEP ? 1 : 0, wq[1]);
    loadWd(2 < NSTEP ? 2 : 0, wq[2]);
    stage(0, 0);
    __syncthreads();

    for (int chunk = 0; chunk < CHUNKS; ++chunk) {
        const int cur = chunk & 1;
        if (chunk + 1 < CHUNKS) stage(chunk + 1, cur ^ 1);   // issue; fly under MFMAs
#pragma unroll
        for (int tap = 0; tap < 9; ++tap) {
            const int step = chunk*9 + tap;
            const int slot = tap % 3;                        // static after unroll
            short8 wa0 = wq[slot][0], wa1 = wq[slot][1], wa2 = wq[slot][2];
            int pf = step + 3; if (pf >= NSTEP) pf = NSTEP - 1;
            loadWd(pf, wq[slot]);                            // depth-3 prefetch
            const int kh = tap / 3, kw = tap - kh*3;
            const int n = lane & 15, gw = lane >> 4;
#pragma unroll
            for (int r = 0; r < RWAVE; ++r) {
#pragma unroll
                for (int xh = 0; xh < 2; ++xh) {
                    int pos = (wp*RWAVE + r + kh)*34 + (xh*16 + n + kw);
                    int g = (gw ^ pos) & 3;
                    short8 bfrag = *(const short8*)(&xs[cur][pos*32 + g*8]);
                    int f = r*2 + xh;
                    acc[0][f] = __builtin_amdgcn_mfma_f32_16x16x32_bf16(wa0, bfrag, acc[0][f], 0, 0, 0);
                    acc[1][f] = __builtin_amdgcn_mfma_f32_16x16x32_bf16(wa1, bfrag, acc[1][f], 0, 0, 0);
                    acc[2][f] = __builtin_amdgcn_mfma_f32_16x16x32_bf16(wa2, bfrag, acc[2][f], 0, 0, 0);
                }
            }
        }
        __syncthreads();   // drains stage(next); protects xs[cur] reuse
    }

    // epilogue: C/D layout col=lane&15 (pixel), row=(lane>>4)*4+reg (cout).
    const int n = lane & 15, gw = lane >> 4;
    if (j.mode[which] == 1) {
        unsigned short* out = j.out[which];
#pragma unroll
        for (int a = 0; a < 3; ++a)
#pragma unroll
        for (int r = 0; r < RWAVE; ++r)
#pragma unroll
        for (int xh = 0; xh < 2; ++xh) {
            int y = y0 + wp*RWAVE + r, x = x0 + xh*16 + n;
#pragma unroll
            for (int reg = 0; reg < 4; ++reg) {
                int co = wm*48 + a*16 + gw*4 + reg;
                out[((size_t)(b*96 + co))*HW_ + y*96 + x] = f2bf(acc[a][r*2+xh][reg]);
            }
        }
    } else {
        unsigned short* out = j.out[which];  // padded NHWC, 96 ch
#pragma unroll
        for (int a = 0; a < 3; ++a)
#pragma unroll
        for (int r = 0; r < RWAVE; ++r)
#pragma unroll
        for (int xh = 0; xh < 2; ++xh) {
            int y = y0 + wp*RWAVE + r, x = x0 + xh*16 + n;
            int cb = wm*48 + a*16 + gw*4;
            f32x4 v = acc[a][r*2+xh];
            uint2 pv;
            pv.x = (unsigned)f2bf(v[0]) | ((unsigned)f2bf(v[1]) << 16);
            pv.y = (unsigned)f2bf(v[2]) | ((unsigned)f2bf(v[3]) << 16);
            *(uint2*)(out + ((size_t)(b*PAD_ + y+1)*PAD_ + (x+1))*96 + cb) = pv;
        }
    }

    // fused BN partial sums (y1/y2/y3 jobs): per-cout sum & sumsq from f32 acc.
    if (j.dobn[which]) {
        float* lds_s = (float*)&xs[0][0];
        float* lds_q = lds_s + 96;
        if (tid < 192) lds_s[tid] = 0.f;
        __syncthreads();
#pragma unroll
        for (int a = 0; a < 3; ++a)
#pragma unroll
        for (int reg = 0; reg < 4; ++reg) {
            float s = 0.f, q2 = 0.f;
#pragma unroll
            for (int f = 0; f < 2*RWAVE; ++f) { float v = acc[a][f][reg]; s += v; q2 += v*v; }
#pragma unroll
            for (int m = 1; m < 16; m <<= 1) {
                s  += __shfl_xor(s, m);
                q2 += __shfl_xor(q2, m);
            }
            if (n == 0) {
                int co = wm*48 + a*16 + gw*4 + reg;
                atomicAdd(&lds_s[co], s);
                atomicAdd(&lds_q[co], q2);
            }
        }
        __syncthreads();
        if (tid < 96) {
            int t = j.bnslot[which];
            atomicAdd(stats_raw + t*96 + tid, lds_s[tid]);
            atomicAdd(stats_raw + 288 + t*96 + tid, lds_q[tid]);
        }
    }
}

// ---------------------------------------------------------------------------
// Repack q,k NCHW bf16 -> tap-major [b][tap(9)][ch(96)][L=1024] via LDS.
__global__ __launch_bounds__(256) void repack_qk_kernel(
    const unsigned short* __restrict__ qb, const unsigned short* __restrict__ kb,
    unsigned short* __restrict__ qt, unsigned short* __restrict__ kt)
{
    __shared__ unsigned short q_lds[HW_], k_lds[HW_];
    const int tid = threadIdx.x;
    const int ch = blockIdx.x, b = blockIdx.y;
    const unsigned short* qsrc = qb + ((size_t)(b*96 + ch))*HW_;
    const unsigned short* ksrc = kb + ((size_t)(b*96 + ch))*HW_;
    for (int i = tid; i < HW_/8; i += 256) {
        *(short8*)(&q_lds[i*8]) = *(const short8*)(qsrc + i*8);
        *(short8*)(&k_lds[i*8]) = *(const short8*)(ksrc + i*8);
    }
    __syncthreads();
    const int l0 = tid*4;
    const int i0 = l0 >> 5, j0 = l0 & 31;
    for (int tap = 0; tap < 9; ++tap) {
        int kh = tap/3, kw = tap - kh*3;
        int base = (3*i0 + kh)*96 + kw;
        ushort4 vq, vk;
        vq.x = q_lds[base + 3*(j0+0)]; vq.y = q_lds[base + 3*(j0+1)];
        vq.z = q_lds[base + 3*(j0+2)]; vq.w = q_lds[base + 3*(j0+3)];
        vk.x = k_lds[base + 3*(j0+0)]; vk.y = k_lds[base + 3*(j0+1)];
        vk.z = k_lds[base + 3*(j0+2)]; vk.w = k_lds[base + 3*(j0+3)];
        size_t dst = (((size_t)(b*9 + tap))*96 + ch)*1024 + l0;
        *(ushort4*)(qt + dst) = vq;
        *(ushort4*)(kt + dst) = vk;
    }
}

// ---------------------------------------------------------------------------
// Gram partial: attnp[s][b][tap][cq][ck], L-split s in 0..3.
__global__ __launch_bounds__(256) void attn_mfma_kernel(
    const unsigned short* __restrict__ qt, const unsigned short* __restrict__ kt,
    float* __restrict__ attnp)
{
    __shared__ __align__(16) unsigned short qs[6144], ks[6144];
    const int tid = threadIdx.x, lane = tid & 63, wid = tid >> 6;
    const int tap = blockIdx.x, b = blockIdx.y, s = blockIdx.z;
    const int wm = wid & 1, wn = wid >> 1;
    const unsigned short* qbase = qt + ((size_t)(b*9 + tap))*96*1024;
    const unsigned short* kbase = kt + ((size_t)(b*9 + tap))*96*1024;

    f32x4 acc[3][3];
    f32x4 zero = {0.f, 0.f, 0.f, 0.f};
#pragma unroll
    for (int i = 0; i < 3; ++i)
#pragma unroll
        for (int j = 0; j < 3; ++j) acc[i][j] = zero;

    const int lrow = lane >> 3, lgr = lane & 7;
    for (int kc = 0; kc < 4; ++kc) {
        int L0 = s*256 + kc*64;
        for (int r = wid; r < 12; r += 4) {
            int row = r*8 + lrow;
            int gsrc = lgr ^ (row & 7);             // both-sides XOR swizzle
            gll16(qbase + (size_t)row*1024 + L0 + gsrc*8, &qs[r*512]);
        }
        for (int r = wid; r < 12; r += 4) {
            int row = r*8 + lrow;
            int gsrc = lgr ^ (row & 7);
            gll16(kbase + (size_t)row*1024 + L0 + gsrc*8, &ks[r*512]);
        }
        __syncthreads();
#pragma unroll
        for (int ks_ = 0; ks_ < 2; ++ks_) {
            short8 av[3], bv[3];
#pragma unroll
            for (int am = 0; am < 3; ++am) {
                int row = wm*48 + am*16 + (lane & 15);
                int gp = (ks_*4 + (lane >> 4)) ^ (row & 7);
                av[am] = *(const short8*)(&qs[row*64 + gp*8]);
            }
#pragma unroll
            for (int bn = 0; bn < 3; ++bn) {
                int row = wn*48 + bn*16 + (lane & 15);
                int gp = (ks_*4 + (lane >> 4)) ^ (row & 7);
                bv[bn] = *(const short8*)(&ks[row*64 + gp*8]);
            }
#pragma unroll
            for (int am = 0; am < 3; ++am)
#pragma unroll
                for (int bn = 0; bn < 3; ++bn)
                    acc[am][bn] = __builtin_amdgcn_mfma_f32_16x16x32_bf16(av[am], bv[bn], acc[am][bn], 0, 0, 0);
        }
        __syncthreads();
    }
    float* dst = attnp + ((((size_t)s*8 + b)*9 + tap))*9216;
#pragma unroll
    for (int am = 0; am < 3; ++am)
#pragma unroll
    for (int bn = 0; bn < 3; ++bn)
#pragma unroll
    for (int reg = 0; reg < 4; ++reg) {
        int cq = wm*48 + am*16 + (lane>>4)*4 + reg;
        int ck = wn*48 + bn*16 + (lane&15);
        dst[(size_t)cq*96 + ck] = acc[am][bn][reg];
    }
}

// ---------------------------------------------------------------------------
// softmax over m=(cq*9+tap); emits bf16 per-batch conv weights fragment-linear.
__global__ __launch_bounds__(256) void softmax_kernel(
    const float* __restrict__ attnp, unsigned short* __restrict__ wfab)
{
    __shared__ float red[256];
    const int tid = threadIdx.x;
    const int ck = blockIdx.x % 96, b = blockIdx.x / 96;
    const float scale = 0.03402069087198858f;   // 1/sqrt(864)
    float v[4];
#pragma unroll
    for (int r = 0; r < 4; ++r) {
        int m = r*256 + tid;
        if (m < 864) {
            int cq = m / 9, tap = m - cq*9;
            const float* ap = attnp + ((((size_t)b*9 + tap))*96 + cq)*96 + ck;
            v[r] = (ap[0] + ap[663552] + ap[2*663552] + ap[3*663552]) * scale;
        } else v[r] = -1e30f;
    }
    float mx = fmaxf(fmaxf(v[0], v[1]), fmaxf(v[2], v[3]));
    red[tid] = mx; __syncthreads();
    for (int s = 128; s > 0; s >>= 1) {
        if (tid < s) red[tid] = fmaxf(red[tid], red[tid+s]);
        __syncthreads();
    }
    mx = red[0]; __syncthreads();
    float e[4]; float lsum = 0.f;
#pragma unroll
    for (int r = 0; r < 4; ++r) {
        int m = r*256 + tid;
        if (m < 864) { e[r] = __expf(v[r] - mx); lsum += e[r]; }
        else e[r] = 0.f;
    }
    red[tid] = lsum; __syncthreads();
    for (int s = 128; s > 0; s >>= 1) {
        if (tid < s) red[tid] += red[tid+s];
        __syncthreads();
    }
    float inv = 1.f / red[0];
#pragma unroll
    for (int r = 0; r < 4; ++r) {
        int m = r*256 + tid;
        if (m < 864) {
            int cq = m / 9, tap = m - cq*9;
            int chunk = cq >> 5, cl = cq & 31, g = cl >> 3, j = cl & 7;
            int mf = ck >> 4, mrem = ck & 15;
            int lane2 = mrem + (g << 4);
            size_t oidx = (size_t)b*82944
                + ((((size_t)(chunk*9 + tap)*6 + mf)*64 + lane2)*8 + j);
            wfab[oidx] = f2bf(e[r]*inv);
        }
    }
}

// ---------------------------------------------------------------------------
// out0 = x + concat(bn(y1)*bn(y2), bn(y3)); out1 = x. BN stats computed
// inline from the conv-fused raw sums (s, s2) per channel.
__global__ __launch_bounds__(256) void final_kernel(
    const float* __restrict__ x1, const float* __restrict__ x2,
    const unsigned short* __restrict__ y1, const unsigned short* __restrict__ y2,
    const unsigned short* __restrict__ y3, const float* __restrict__ stats_raw,
    float* __restrict__ out)
{
    size_t q4 = (size_t)blockIdx.x*256 + threadIdx.x;  // quad id < 1769472
    size_t base = q4*4;
    int b  = (int)(base / CHW_);
    int c  = (int)((base / HW_) % 96);
    int hw = (int)(base % HW_);
    const float NN = 73728.f;
    float s1 = stats_raw[c],        qq1 = stats_raw[288 + c];
    float s2 = stats_raw[96 + c],   qq2 = stats_raw[384 + c];
    float s3 = stats_raw[192 + c],  qq3 = stats_raw[480 + c];
    float mu1 = s1/NN, mu2 = s2/NN, mu3 = s3/NN;
    float r1 = rsqrtf(qq1/NN - mu1*mu1 + 1e-5f);
    float r2 = rsqrtf(qq2/NN - mu2*mu2 + 1e-5f);
    float r3 = rsqrtf(qq3/NN - mu3*mu3 + 1e-5f);
    float4 x1v = *(const float4*)(x1 + base);
    float4 x2v = *(const float4*)(x2 + base);
    ushort4 a1 = *(const ushort4*)(y1 + base);
    ushort4 a2 = *(const ushort4*)(y2 + base);
    ushort4 a3 = *(const ushort4*)(y3 + base);
    size_t lo = ((size_t)(b*192 + c))*HW_ + hw;
    size_t hi = lo + (size_t)96*HW_;
    float4 o0, o1;
    o0.x = x1v.x + ((bf2f(a1.x)-mu1)*r1) * ((bf2f(a2.x)-mu2)*r2);
    o0.y = x1v.y + ((bf2f(a1.y)-mu1)*r1) * ((bf2f(a2.y)-mu2)*r2);
    o0.z = x1v.z + ((bf2f(a1.z)-mu1)*r1) * ((bf2f(a2.z)-mu2)*r2);
    o0.w = x1v.w + ((bf2f(a1.w)-mu1)*r1) * ((bf2f(a2.w)-mu2)*r2);
    o1.x = x2v.x + (bf2f(a3.x)-mu3)*r3;
    o1.y = x2v.y + (bf2f(a3.y)-mu3)*r3;
    o1.z = x2v.z + (bf2f(a3.z)-mu3)*r3;
    o1.w = x2v.w + (bf2f(a3.w)-mu3)*r3;
    *(float4*)(out + lo) = o0;
    *(float4*)(out + hi) = o1;
    *(float4*)(out + OUTHALF_ + lo) = x1v;
    *(float4*)(out + OUTHALF_ + hi) = x2v;
}

// ---------------------------------------------------------------------------
extern "C" void kernel_launch(void* const* d_in, const int* in_sizes, int n_in,
                              void* d_out, int out_size, void* d_ws, size_t ws_size,
                              hipStream_t stream)
{
    const float* x1  = (const float*)d_in[0];
    const float* x2  = (const float*)d_in[1];
    const float* w1  = (const float*)d_in[2];
    const float* w2  = (const float*)d_in[3];
    const float* wa1 = (const float*)d_in[4];
    const float* wa2 = (const float*)d_in[5];
    const float* wa3 = (const float*)d_in[6];
    float* out = (float*)d_out;
    char* ws = (char*)d_ws;

    unsigned short* xb   = (unsigned short*)(ws);             // 29,503,488 B
    unsigned short* y1b  = (unsigned short*)(ws + 29503488);  // 14,155,776 B
    unsigned short* y2b  = (unsigned short*)(ws + 43659264);
    unsigned short* y3b  = (unsigned short*)(ws + 57815040);
    unsigned short* wf1  = (unsigned short*)(ws + 71970816);  // 165,888 B
    unsigned short* wf2  = (unsigned short*)(ws + 72136704);
    unsigned short* wfa1 = (unsigned short*)(ws + 72302592);  // 331,776 B
    unsigned short* wfa2 = (unsigned short*)(ws + 72634368);
    unsigned short* wfa3 = (unsigned short*)(ws + 72966144);
    unsigned short* wfab = (unsigned short*)(ws + 73297920);  // 1,327,104 B
    float* stats_raw = (float*)(ws + 74625024);               // 2,304 B

    // d_out scratch (all dead before final_kernel):
    unsigned short* qb    = (unsigned short*)out;                       // 14,155,776 B
    unsigned short* kkb   = (unsigned short*)((char*)out + 14155776);   // 14,155,776 B
    unsigned short* vb    = (unsigned short*)((char*)out + 28311552);   // 14,751,744 B
    unsigned short* qt    = (unsigned short*)((char*)out + 43063296);   // 14,155,776 B
    unsigned short* kt    = (unsigned short*)((char*)out + 57219072);   // 14,155,776 B
    float*          attnp = (float*)((char*)out + 71374848);            // 10,616,832 B

    pack_w_all_kernel<<<2592, 256, 0, stream>>>(w1, w2, wa1, wa2, wa3,
                                                wf1, wf2, wfa1, wfa2, wfa3,
                                                stats_raw);
    pack_x_kernel<<<dim3(99, 8), 256, 0, stream>>>(x1, x2, xb, vb);

    ConvJobs jA;
    jA.xin[0]=xb;  jA.wf[0]=wfa1; jA.out[0]=qb;  jA.chunks[0]=6; jA.ci0[0]=0;  jA.mode[0]=1; jA.wstride[0]=0; jA.cistr[0]=192; jA.dobn[0]=0; jA.bnslot[0]=0;
    jA.xin[1]=xb;  jA.wf[1]=wfa2; jA.out[1]=kkb; jA.chunks[1]=6; jA.ci0[1]=0;  jA.mode[1]=1; jA.wstride[1]=0; jA.cistr[1]=192; jA.dobn[1]=0; jA.bnslot[1]=0;
    jA.xin[2]=xb;  jA.wf[2]=wfa3; jA.out[2]=vb;  jA.chunks[2]=6; jA.ci0[2]=0;  jA.mode[2]=2; jA.wstride[2]=0; jA.cistr[2]=192; jA.dobn[2]=0; jA.bnslot[2]=0;
    jA.xin[3]=xb;  jA.wf[3]=wf1;  jA.out[3]=y1b; jA.chunks[3]=3; jA.ci0[3]=0;  jA.mode[3]=1; jA.wstride[3]=0; jA.cistr[3]=192; jA.dobn[3]=1; jA.bnslot[3]=0;
    jA.xin[4]=xb;  jA.wf[4]=wf2;  jA.out[4]=y2b; jA.chunks[4]=3; jA.ci0[4]=96; jA.mode[4]=1; jA.wstride[4]=0; jA.cistr[4]=192; jA.dobn[4]=1; jA.bnslot[4]=1;
    conv_mfma_kernel<8><<<dim3(3, 12, 40), 256, 0, stream>>>(jA, stats_raw, 5);

    repack_qk_kernel<<<dim3(96, 8), 256, 0, stream>>>(qb, kkb, qt, kt);
    attn_mfma_kernel<<<dim3(9, 8, 4), 256, 0, stream>>>(qt, kt, attnp);
    softmax_kernel<<<768, 256, 0, stream>>>(attnp, wfab);

    ConvJobs jB;
    for (int s = 0; s < 5; ++s) {
        jB.xin[s]=vb; jB.wf[s]=wfab; jB.out[s]=y3b; jB.chunks[s]=3; jB.ci0[s]=0;
        jB.mode[s]=1; jB.wstride[s]=82944; jB.cistr[s]=96; jB.dobn[s]=1; jB.bnslot[s]=2;
    }
    conv_mfma_kernel<4><<<dim3(3, 24, 8), 256, 0, stream>>>(jB, stats_raw, 1);

    final_kernel<<<6912, 256, 0, stream>>>(x1, x2, y1b, y2b, y3b, stats_raw, out);
}